// Round 1
// baseline (355.010 us; speedup 1.0000x reference)
//
#include <hip/hip_runtime.h>

// 6-point periodic stencil + DGPE ODE RHS on a 192^3 lattice.
// Neighbor indices computed arithmetically (saves 170 MB of index reads).
// Input order: t, y, J, anisotropy, gamma, h_dis_x, h_dis_y, beta,
//              e_disorder, nn_idx_1..nn_idz_2 (index arrays unused).

#define LDIM 192
#define LSQ  (LDIM * LDIM)          // 36864
#define NTOT (LDIM * LDIM * LDIM)   // 7077888 = 256 * 27648

__global__ __launch_bounds__(256) void dgpe_kernel(
    const float* __restrict__ y,
    const float* __restrict__ Jarr,
    const float* __restrict__ aniso,
    const float* __restrict__ gam,
    const float* __restrict__ hdx,
    const float* __restrict__ hdy,
    const float* __restrict__ beta,
    const float* __restrict__ edis,
    float* __restrict__ out)
{
    const int i = blockIdx.x * blockDim.x + threadIdx.x;
    if (i >= NTOT) return;

    const float* __restrict__ x = y;
    const float* __restrict__ p = y + NTOT;

    // decompose i = a*L^2 + b*L + c (compiler emits magic-multiply for /192)
    const unsigned ui  = (unsigned)i;
    const unsigned a   = ui / LSQ;
    const unsigned rem = ui - a * LSQ;
    const unsigned b   = rem / LDIM;
    const unsigned c   = rem - b * LDIM;

    // periodic neighbors (flat offsets with wrap)
    const int xm = (a == 0)        ? i + (LDIM - 1) * LSQ  : i - LSQ;
    const int xp = (a == LDIM - 1) ? i - (LDIM - 1) * LSQ  : i + LSQ;
    const int ym = (b == 0)        ? i + (LDIM - 1) * LDIM : i - LDIM;
    const int yp = (b == LDIM - 1) ? i - (LDIM - 1) * LDIM : i + LDIM;
    const int zm = (c == 0)        ? i + (LDIM - 1)        : i - 1;
    const int zp = (c == LDIM - 1) ? i - (LDIM - 1)        : i + 1;

    const float Ji = Jarr[i];
    const float an = aniso[i];
    const float xi = x[i];
    const float pi = p[i];

    const float xL = Ji * (x[xm] + x[xp] + x[ym] + x[yp] + an * (x[zm] + x[zp]));
    const float yL = Ji * (p[xm] + p[xp] + p[ym] + p[yp] + an * (p[zm] + p[zp]));

    const float g  = gam[i];
    const float ed = edis[i];
    const float bt = beta[i];

    const float r2    = xi * xi + pi * pi;
    const float cross = xL * pi - yL * xi;

    const float dx =  g * pi * cross + ed * pi - yL + hdy[i] + bt * r2 * pi;
    const float dp = -g * xi * cross - ed * xi + xL - hdx[i] - bt * r2 * xi;

    out[i]        = dx;
    out[i + NTOT] = dp;
}

extern "C" void kernel_launch(void* const* d_in, const int* in_sizes, int n_in,
                              void* d_out, int out_size, void* d_ws, size_t ws_size,
                              hipStream_t stream) {
    // d_in: 0=t, 1=y, 2=J, 3=anisotropy, 4=gamma, 5=h_dis_x, 6=h_dis_y,
    //       7=beta, 8=e_disorder, 9..14=neighbor index arrays (unused)
    const float* y_    = (const float*)d_in[1];
    const float* Jarr  = (const float*)d_in[2];
    const float* aniso = (const float*)d_in[3];
    const float* gam   = (const float*)d_in[4];
    const float* hdx   = (const float*)d_in[5];
    const float* hdy   = (const float*)d_in[6];
    const float* beta  = (const float*)d_in[7];
    const float* edis  = (const float*)d_in[8];
    float* out = (float*)d_out;

    const int threads = 256;
    const int blocks  = NTOT / threads;  // 27648, exact
    dgpe_kernel<<<blocks, threads, 0, stream>>>(y_, Jarr, aniso, gam, hdx, hdy,
                                                beta, edis, out);
}